// Round 1
// baseline (230.334 us; speedup 1.0000x reference)
//
#include <hip/hip_runtime.h>

// Zero timestep t within each PERIOD=4 frame where (t & 3) == mask_idx.
// x: [B=8, T=8192, D=512] fp32, contiguous. Pure memory-bound elementwise op.
//
// D = 512 floats = 128 float4 per timestep -> t = float4_idx >> 7.
// One wave (64 lanes * 16B) covers 1 KiB = half a timestep, so the mask
// predicate is wave-uniform: masked waves skip the load entirely.

#define PERIOD 4

__global__ __launch_bounds__(256)
void pd_mask_kernel(const float4* __restrict__ x,
                    const int* __restrict__ mask_p,
                    float4* __restrict__ out,
                    int n4) {
    const int m = *mask_p;  // single-element input; L2-hit broadcast
    const float4 zero = make_float4(0.f, 0.f, 0.f, 0.f);
    const int stride = gridDim.x * blockDim.x;
    for (int i = blockIdx.x * blockDim.x + threadIdx.x; i < n4; i += stride) {
        const int t = i >> 7;                 // 128 float4 per timestep (D=512)
        if ((t & (PERIOD - 1)) == m) {
            out[i] = zero;                    // no load for masked timesteps
        } else {
            out[i] = x[i];
        }
    }
}

extern "C" void kernel_launch(void* const* d_in, const int* in_sizes, int n_in,
                              void* d_out, int out_size, void* d_ws, size_t ws_size,
                              hipStream_t stream) {
    const float4* x      = (const float4*)d_in[0];
    const int*    mask_p = (const int*)d_in[1];
    float4*       out    = (float4*)d_out;

    const int n4 = out_size / 4;              // 33554432 / 4 = 8388608 float4
    const int block = 256;
    int grid = (n4 + block - 1) / block;
    if (grid > 2048) grid = 2048;             // grid-stride the rest

    pd_mask_kernel<<<grid, block, 0, stream>>>(x, mask_p, out, n4);
}